// Round 1
// baseline (26374.783 us; speedup 1.0000x reference)
//
#include <hip/hip_runtime.h>
#include <stdint.h>

#define B_ 128
#define T_ 1024
#define D_ 256
#define H_ 512
#define C_ 1000
#define GB 8          // batch groups (16 rows each)
#define GH 32         // hidden-column groups (16 units each)
#define ROWS 16       // batch rows per WG
#define UN 16         // hidden units per WG
#define KTOT (H_ + D_)   // 768: fused [h | x] K dimension
#define NCOL 64          // 4 gates * UN
#define LDK (KTOT + 8)   // padded LDS row stride (bank-conflict balance)

typedef __bf16 bf16x8 __attribute__((ext_vector_type(8)));
typedef float f32x4 __attribute__((ext_vector_type(4)));

__device__ __forceinline__ uint16_t f2bf(float f) {
  uint32_t u = __float_as_uint(f);
  u += 0x7FFFu + ((u >> 16) & 1u);   // RNE
  return (uint16_t)(u >> 16);
}
__device__ __forceinline__ float bf2f(uint16_t b) {
  return __uint_as_float(((uint32_t)b) << 16);
}
__device__ __forceinline__ float sigm(float x) { return 1.0f / (1.0f + __expf(-x)); }
__device__ __forceinline__ float tanhfast(float x) { return 2.0f / (1.0f + __expf(-2.0f * x)) - 1.0f; }

// Persistent scan kernel: 256 WGs (1 per CU), 256 threads each.
// WG (bb, cg): batch rows [bb*16, bb*16+16), hidden units [cg*16, cg*16+16) for all 4 gates.
// Per step: GEMM [16, 768] @ [768, 64] via mfma_f32_16x16x32_bf16 (wave w = gate w),
// then gates/cell update, publish h-slice + flag (agent scope).
__global__ __launch_bounds__(256, 1) void lstm_scan(
    const float* __restrict__ x,
    const float* __restrict__ Wgx, const float* __restrict__ Wgh, const float* __restrict__ bg,
    const float* __restrict__ Wix, const float* __restrict__ Wih, const float* __restrict__ bi,
    const float* __restrict__ Wfx, const float* __restrict__ Wfh, const float* __restrict__ bf_,
    const float* __restrict__ Wox, const float* __restrict__ Woh, const float* __restrict__ bo,
    uint16_t* __restrict__ hring,   // [2][B_][H_] bf16
    int* __restrict__ flags)        // [GB][GH], memset to 0 before launch
{
  __shared__ __align__(16) uint16_t WtL[NCOL * LDK];  // Bt[n][k] bf16, 99328 B
  __shared__ __align__(16) uint16_t AL[ROWS * LDK];   // A[m][k] bf16: [h | x], 24832 B
  __shared__ float gbuf[4 * ROWS * UN];               // gate pre-acts, 4096 B
  __shared__ float cL[ROWS * UN];                     // cell state, 1024 B
  __shared__ float biasL[NCOL];                       // 256 B

  const int tid = threadIdx.x;
  const int wg  = blockIdx.x;
  const int bb  = wg & 7;     // batch group: wg%8 so a bb-group tends to share an XCD
  const int cg  = wg >> 3;    // column group 0..31
  const int b0  = bb * ROWS;
  const int u0  = cg * UN;

  const float* Whs[4] = {Wgh, Wih, Wfh, Woh};
  const float* Wxs[4] = {Wgx, Wix, Wfx, Wox};

  // ---- load weight slice into LDS (transposed: Wt[n][k]) ----
  {
    const int n    = tid & 63;
    const int kk   = tid >> 6;        // 0..3
    const int gate = n >> 4;
    const int j    = u0 + (n & 15);
    const float* WhP = Whs[gate];
    const float* WxP = Wxs[gate];
    for (int k4 = 0; k4 < KTOT; k4 += 4) {
      int k = k4 + kk;
      float w = (k < H_) ? WhP[(size_t)k * H_ + j] : WxP[(size_t)(k - H_) * H_ + j];
      WtL[n * LDK + k] = f2bf(w);
    }
  }
  if (tid < NCOL) {
    const float* bs[4] = {bg, bi, bf_, bo};
    biasL[tid] = bs[tid >> 4][u0 + (tid & 15)];
  }
  cL[tid] = 0.0f;

  const int sr = tid >> 4;   // staging row 0..15
  const int sj = tid & 15;   // staging chunk 0..15

  // zero A h-region for t=0 (h[0] == 0; never read from global)
  {
    uint4 z; z.x = z.y = z.z = z.w = 0u;
    uint4* zp = (uint4*)&AL[sr * LDK + sj * 32];
    zp[0] = z; zp[1] = z; zp[2] = z; zp[3] = z;
  }

  const int lane = tid & 63;
  const int wv   = tid >> 6;          // wave = gate
  const int l15  = lane & 15;
  const int q    = lane >> 4;
  const uint16_t* Abase = &AL[l15 * LDK + q * 8];
  const uint16_t* Bbase = &WtL[(wv * UN + l15) * LDK + q * 8];

  for (int t = 0; t < T_; ++t) {
    // ---- wait for + stage h[t] ----
    if (t > 0) {
      if (tid < GH) {
        while (__hip_atomic_load(&flags[bb * GH + tid], __ATOMIC_ACQUIRE,
                                 __HIP_MEMORY_SCOPE_AGENT) < t) {
          __builtin_amdgcn_s_sleep(1);
        }
      }
      __syncthreads();
      const uint4* srcp = (const uint4*)(hring + ((size_t)(t & 1) * B_ + b0 + sr) * H_ + sj * 32);
      uint4* dstp = (uint4*)&AL[sr * LDK + sj * 32];
      dstp[0] = srcp[0]; dstp[1] = srcp[1]; dstp[2] = srcp[2]; dstp[3] = srcp[3];
    }
    // ---- stage x[t] (fp32 -> bf16) ----
    {
      const float* xsrc = x + ((size_t)(b0 + sr) * T_ + t) * D_ + sj * 16;
      float4 f0 = ((const float4*)xsrc)[0];
      float4 f1 = ((const float4*)xsrc)[1];
      float4 f2 = ((const float4*)xsrc)[2];
      float4 f3 = ((const float4*)xsrc)[3];
      uint4 o0, o1;
      o0.x = f2bf(f0.x) | ((uint32_t)f2bf(f0.y) << 16);
      o0.y = f2bf(f0.z) | ((uint32_t)f2bf(f0.w) << 16);
      o0.z = f2bf(f1.x) | ((uint32_t)f2bf(f1.y) << 16);
      o0.w = f2bf(f1.z) | ((uint32_t)f2bf(f1.w) << 16);
      o1.x = f2bf(f2.x) | ((uint32_t)f2bf(f2.y) << 16);
      o1.y = f2bf(f2.z) | ((uint32_t)f2bf(f2.w) << 16);
      o1.z = f2bf(f3.x) | ((uint32_t)f2bf(f3.y) << 16);
      o1.w = f2bf(f3.z) | ((uint32_t)f2bf(f3.w) << 16);
      uint4* xdst = (uint4*)&AL[sr * LDK + H_ + sj * 16];
      xdst[0] = o0; xdst[1] = o1;
    }
    __syncthreads();

    // ---- GEMM: wave wv computes gate wv pre-acts [16 rows, 16 units] ----
    f32x4 acc = {0.f, 0.f, 0.f, 0.f};
#pragma unroll 4
    for (int k0 = 0; k0 < KTOT; k0 += 32) {
      bf16x8 a = *(const bf16x8*)(Abase + k0);
      bf16x8 b = *(const bf16x8*)(Bbase + k0);
      acc = __builtin_amdgcn_mfma_f32_16x16x32_bf16(a, b, acc, 0, 0, 0);
    }
    // D layout: row(batch) = q*4+r, col(unit) = lane&15
#pragma unroll
    for (int r = 0; r < 4; ++r) {
      gbuf[wv * (ROWS * UN) + (q * 4 + r) * UN + l15] = acc[r];
    }
    __syncthreads();

    // ---- pointwise update: thread -> (row, unit) ----
    {
      const int rr = tid >> 4, uu = tid & 15;
      const int o  = rr * UN + uu;
      float pg = gbuf[0 * (ROWS * UN) + o] + biasL[uu];
      float pi = gbuf[1 * (ROWS * UN) + o] + biasL[16 + uu];
      float pf = gbuf[2 * (ROWS * UN) + o] + biasL[32 + uu];
      float po = gbuf[3 * (ROWS * UN) + o] + biasL[48 + uu];
      float g  = tanhfast(pg);
      float ii = sigm(pi);
      float ff = sigm(pf);
      float oo = sigm(po);
      float c  = g * ii + cL[o] * ff;
      cL[o] = c;
      float h = tanhfast(c) * oo;
      hring[((size_t)((t + 1) & 1) * B_ + b0 + rr) * H_ + u0 + uu] = f2bf(h);
    }
    __threadfence();     // make h-slice visible at agent scope
    __syncthreads();     // all threads' fences done before flag
    if (tid == 0) {
      __hip_atomic_store(&flags[bb * GH + cg], t + 1, __ATOMIC_RELEASE,
                         __HIP_MEMORY_SCOPE_AGENT);
    }
  }
}

// Final projection: out[b,c] = sum_k h[b,k] * Wph[k,c] + bp[c]
__global__ __launch_bounds__(256) void lstm_proj(
    const uint16_t* __restrict__ hfin,   // [B_][H_] bf16
    const float* __restrict__ Wph,       // [H_][C_]
    const float* __restrict__ bp,        // [C_]
    float* __restrict__ out)             // [B_][C_]
{
  __shared__ float hL[8 * H_];   // 16 KB
  const int tid = threadIdx.x;
  const int b0  = blockIdx.y * 8;
  const int c   = blockIdx.x * 256 + tid;

  // stage 8 rows of h as fp32
  {
    int idx = tid * 16;   // 4096 elems / 256 threads = 16 each
#pragma unroll
    for (int e = 0; e < 16; ++e) {
      int i = idx + e;
      hL[i] = bf2f(hfin[(size_t)(b0 + (i >> 9)) * H_ + (i & 511)]);
    }
  }
  __syncthreads();

  if (c < C_) {
    float acc[8] = {0.f, 0.f, 0.f, 0.f, 0.f, 0.f, 0.f, 0.f};
#pragma unroll 8
    for (int k = 0; k < H_; ++k) {
      float w = Wph[(size_t)k * C_ + c];
#pragma unroll
      for (int rb = 0; rb < 8; ++rb) acc[rb] += hL[rb * H_ + k] * w;
    }
    float bias = bp[c];
#pragma unroll
    for (int rb = 0; rb < 8; ++rb) out[(size_t)(b0 + rb) * C_ + c] = acc[rb] + bias;
  }
}

extern "C" void kernel_launch(void* const* d_in, const int* in_sizes, int n_in,
                              void* d_out, int out_size, void* d_ws, size_t ws_size,
                              hipStream_t stream) {
  const float* x   = (const float*)d_in[0];
  const float* Wgx = (const float*)d_in[1];
  const float* Wgh = (const float*)d_in[2];
  const float* bg  = (const float*)d_in[3];
  const float* Wix = (const float*)d_in[4];
  const float* Wih = (const float*)d_in[5];
  const float* bi  = (const float*)d_in[6];
  const float* Wfx = (const float*)d_in[7];
  const float* Wfh = (const float*)d_in[8];
  const float* bf_ = (const float*)d_in[9];
  const float* Wox = (const float*)d_in[10];
  const float* Woh = (const float*)d_in[11];
  const float* bo  = (const float*)d_in[12];
  const float* Wph = (const float*)d_in[13];
  const float* bp  = (const float*)d_in[14];
  float* out = (float*)d_out;

  // ws layout: [0, 256KB) h ring (2 slots), then flags (1 KB)
  uint16_t* hring = (uint16_t*)d_ws;
  int* flags = (int*)((char*)d_ws + (size_t)2 * B_ * H_ * sizeof(uint16_t));

  hipMemsetAsync(flags, 0, GB * GH * sizeof(int), stream);

  lstm_scan<<<dim3(GB * GH), dim3(256), 0, stream>>>(
      x, Wgx, Wgh, bg, Wix, Wih, bi, Wfx, Wfh, bf_, Wox, Woh, bo, hring, flags);

  // h[T] lives in slot T%2 == 0
  const uint16_t* hfin = hring + (size_t)(T_ & 1) * B_ * H_;
  lstm_proj<<<dim3(4, 16), dim3(256), 0, stream>>>(hfin, Wph, bp, out);
}

// Round 2
// 4759.861 us; speedup vs baseline: 5.5411x; 5.5411x over previous
//
#include <hip/hip_runtime.h>
#include <stdint.h>

#define B_ 128
#define T_ 1024
#define D_ 256
#define H_ 512
#define C_ 1000
#define GB 8          // batch groups (16 rows each)
#define GH 32         // hidden-column groups (16 units each)
#define ROWS 16       // batch rows per WG
#define UN 16         // hidden units per WG
#define KTOT (H_ + D_)   // 768: fused [h | x] K dimension
#define NCOL 64          // 4 gates * UN
#define LDK (KTOT + 8)   // padded LDS row stride

typedef __bf16 bf16x8 __attribute__((ext_vector_type(8)));
typedef float f32x4 __attribute__((ext_vector_type(4)));

__device__ __forceinline__ uint16_t f2bf(float f) {
  uint32_t u = __float_as_uint(f);
  u += 0x7FFFu + ((u >> 16) & 1u);   // RNE
  return (uint16_t)(u >> 16);
}
__device__ __forceinline__ float bf2f(uint16_t b) {
  return __uint_as_float(((uint32_t)b) << 16);
}
__device__ __forceinline__ float sigm(float x) { return 1.0f / (1.0f + __expf(-x)); }
__device__ __forceinline__ float tanhfast(float x) { return 2.0f / (1.0f + __expf(-2.0f * x)) - 1.0f; }

// Persistent scan: 256 WGs (1/CU), 256 threads. WG (bb,cg) owns batch rows
// [bb*16,+16) x hidden units [cg*16,+16) for all 4 gates.
// Cross-WG comms: ALL through LLC via relaxed system-scope atomics (sc0 sc1,
// write-through / L1+L2-bypass). Zero cache-maintenance ops (no wbl2/inv):
// ordering = s_waitcnt vmcnt(0) in the storing wave before one fetch_add to
// a per-batch-group counter. Consumers poll the counter (1 thread) then read
// h slices with system-scope relaxed atomic loads.
__global__ __launch_bounds__(256, 1) void lstm_scan(
    const float* __restrict__ x,
    const float* __restrict__ Wgx, const float* __restrict__ Wgh, const float* __restrict__ bg,
    const float* __restrict__ Wix, const float* __restrict__ Wih, const float* __restrict__ bi,
    const float* __restrict__ Wfx, const float* __restrict__ Wfh, const float* __restrict__ bf_,
    const float* __restrict__ Wox, const float* __restrict__ Woh, const float* __restrict__ bo,
    uint16_t* __restrict__ hring,   // [2][B_][H_] bf16
    int* __restrict__ cnt)          // [GB], zeroed before launch
{
  __shared__ __align__(16) uint16_t WtL[NCOL * LDK];  // Bt[n][k] bf16
  __shared__ __align__(16) uint16_t AL[ROWS * LDK];   // A[m][k] bf16: [h | x]
  __shared__ float gbuf[4 * ROWS * UN];               // gate pre-acts
  __shared__ float cL[ROWS * UN];                     // cell state fp32
  __shared__ float biasL[NCOL];
  __shared__ __align__(8) uint16_t hOutL[ROWS * UN];  // this WG's h slice, bf16

  const int tid = threadIdx.x;
  const int wg  = blockIdx.x;
  const int bb  = wg & 7;
  const int cg  = wg >> 3;
  const int b0  = bb * ROWS;
  const int u0  = cg * UN;

  const float* Whs[4] = {Wgh, Wih, Wfh, Woh};
  const float* Wxs[4] = {Wgx, Wix, Wfx, Wox};

  // ---- load weight slice into LDS (transposed: Wt[n][k]) ----
  {
    const int n    = tid & 63;
    const int kk   = tid >> 6;        // 0..3
    const int gate = n >> 4;
    const int j    = u0 + (n & 15);
    const float* WhP = Whs[gate];
    const float* WxP = Wxs[gate];
    for (int k4 = 0; k4 < KTOT; k4 += 4) {
      int k = k4 + kk;
      float w = (k < H_) ? WhP[(size_t)k * H_ + j] : WxP[(size_t)(k - H_) * H_ + j];
      WtL[n * LDK + k] = f2bf(w);
    }
  }
  if (tid < NCOL) {
    const float* bs[4] = {bg, bi, bf_, bo};
    biasL[tid] = bs[tid >> 4][u0 + (tid & 15)];
  }
  cL[tid] = 0.0f;

  const int sr = tid >> 4;   // staging row 0..15
  const int sj = tid & 15;   // staging chunk 0..15

  // zero A h-region for t=0 (h[0]==0; never read from global)
  {
    uint64_t* zp = (uint64_t*)&AL[sr * LDK + sj * 32];
#pragma unroll
    for (int j = 0; j < 8; ++j) zp[j] = 0ull;
  }

  const int lane = tid & 63;
  const int wv   = tid >> 6;          // wave = gate
  const int l15  = lane & 15;
  const int q    = lane >> 4;
  const uint16_t* Abase = &AL[l15 * LDK + q * 8];
  const uint16_t* Bbase = &WtL[(wv * UN + l15) * LDK + q * 8];

  for (int t = 0; t < T_; ++t) {
    // ---- stage x[t] (fp32 -> bf16), independent of h ----
    {
      const float* xsrc = x + ((size_t)(b0 + sr) * T_ + t) * D_ + sj * 16;
      float4 f0 = ((const float4*)xsrc)[0];
      float4 f1 = ((const float4*)xsrc)[1];
      float4 f2 = ((const float4*)xsrc)[2];
      float4 f3 = ((const float4*)xsrc)[3];
      uint4 o0, o1;
      o0.x = f2bf(f0.x) | ((uint32_t)f2bf(f0.y) << 16);
      o0.y = f2bf(f0.z) | ((uint32_t)f2bf(f0.w) << 16);
      o0.z = f2bf(f1.x) | ((uint32_t)f2bf(f1.y) << 16);
      o0.w = f2bf(f1.z) | ((uint32_t)f2bf(f1.w) << 16);
      o1.x = f2bf(f2.x) | ((uint32_t)f2bf(f2.y) << 16);
      o1.y = f2bf(f2.z) | ((uint32_t)f2bf(f2.w) << 16);
      o1.z = f2bf(f3.x) | ((uint32_t)f2bf(f3.y) << 16);
      o1.w = f2bf(f3.z) | ((uint32_t)f2bf(f3.w) << 16);
      uint4* xdst = (uint4*)&AL[sr * LDK + H_ + sj * 16];
      xdst[0] = o0; xdst[1] = o1;
    }

    // ---- wait for + stage h[t] ----
    if (t > 0) {
      if (tid == 0) {
        const int need = 32 * t;
        while (__hip_atomic_load(&cnt[bb], __ATOMIC_RELAXED,
                                 __HIP_MEMORY_SCOPE_SYSTEM) < need) {
          __builtin_amdgcn_s_sleep(1);
        }
      }
      __syncthreads();
      // thread: row sr, k-range sj*32 .. +31 (64 B = 8 x u64), LLC-direct loads
      const uint64_t* hsrc =
          (const uint64_t*)(hring + ((size_t)(t & 1) * B_ + b0 + sr) * H_) + sj * 8;
      uint64_t v[8];
#pragma unroll
      for (int j = 0; j < 8; ++j)
        v[j] = __hip_atomic_load(hsrc + j, __ATOMIC_RELAXED, __HIP_MEMORY_SCOPE_SYSTEM);
      uint64_t* adst = (uint64_t*)&AL[sr * LDK + sj * 32];
#pragma unroll
      for (int j = 0; j < 8; ++j) adst[j] = v[j];
    }
    __syncthreads();

    // ---- GEMM: wave wv -> gate wv pre-acts [16 rows, 16 units] ----
    f32x4 acc0 = {0.f, 0.f, 0.f, 0.f};
    f32x4 acc1 = {0.f, 0.f, 0.f, 0.f};
#pragma unroll 3
    for (int k0 = 0; k0 < KTOT; k0 += 64) {
      bf16x8 a0 = *(const bf16x8*)(Abase + k0);
      bf16x8 b0v = *(const bf16x8*)(Bbase + k0);
      bf16x8 a1 = *(const bf16x8*)(Abase + k0 + 32);
      bf16x8 b1v = *(const bf16x8*)(Bbase + k0 + 32);
      acc0 = __builtin_amdgcn_mfma_f32_16x16x32_bf16(a0, b0v, acc0, 0, 0, 0);
      acc1 = __builtin_amdgcn_mfma_f32_16x16x32_bf16(a1, b1v, acc1, 0, 0, 0);
    }
    // D layout: row(batch) = q*4+r, col(unit) = lane&15
#pragma unroll
    for (int r = 0; r < 4; ++r) {
      gbuf[wv * (ROWS * UN) + (q * 4 + r) * UN + l15] = acc0[r] + acc1[r];
    }
    __syncthreads();

    // ---- pointwise update: thread -> (row, unit) ----
    {
      const int rr = tid >> 4, uu = tid & 15;
      const int o  = rr * UN + uu;
      float pg = gbuf[0 * (ROWS * UN) + o] + biasL[uu];
      float pi = gbuf[1 * (ROWS * UN) + o] + biasL[16 + uu];
      float pf = gbuf[2 * (ROWS * UN) + o] + biasL[32 + uu];
      float po = gbuf[3 * (ROWS * UN) + o] + biasL[48 + uu];
      float g  = tanhfast(pg);
      float ii = sigm(pi);
      float ff = sigm(pf);
      float oo = sigm(po);
      float c  = g * ii + cL[o] * ff;
      cL[o] = c;
      float h = tanhfast(c) * oo;
      hOutL[o] = f2bf(h);
    }
    __syncthreads();

    // ---- publish h slice (wave 0 only): write-through LLC stores, then
    //      waitcnt + one counter bump. No fences, no wbl2/inv. ----
    if (tid < 64) {
      const int r  = tid >> 2;       // row 0..15
      const int qq = tid & 3;        // 4-unit chunk
      uint64_t v = *(const uint64_t*)&hOutL[r * UN + qq * 4];
      uint64_t* gdst = (uint64_t*)(hring +
          ((size_t)((t + 1) & 1) * B_ + b0 + r) * H_ + u0) + qq;
      __hip_atomic_store(gdst, v, __ATOMIC_RELAXED, __HIP_MEMORY_SCOPE_SYSTEM);
      asm volatile("s_waitcnt vmcnt(0)" ::: "memory");
      if (tid == 0) {
        __hip_atomic_fetch_add(&cnt[bb], 1, __ATOMIC_RELAXED,
                               __HIP_MEMORY_SCOPE_SYSTEM);
      }
    }
    // next iteration's post-poll barrier separates hOutL reuse
  }
}

// Final projection: out[b,c] = sum_k h[b,k] * Wph[k,c] + bp[c]
__global__ __launch_bounds__(256) void lstm_proj(
    const uint16_t* __restrict__ hfin,   // [B_][H_] bf16
    const float* __restrict__ Wph,       // [H_][C_]
    const float* __restrict__ bp,        // [C_]
    float* __restrict__ out)             // [B_][C_]
{
  __shared__ float hL[8 * H_];   // 16 KB
  const int tid = threadIdx.x;
  const int b0  = blockIdx.y * 8;
  const int c   = blockIdx.x * 256 + tid;

  {
    int idx = tid * 16;
#pragma unroll
    for (int e = 0; e < 16; ++e) {
      int i = idx + e;
      hL[i] = bf2f(hfin[(size_t)(b0 + (i >> 9)) * H_ + (i & 511)]);
    }
  }
  __syncthreads();

  if (c < C_) {
    float acc[8] = {0.f, 0.f, 0.f, 0.f, 0.f, 0.f, 0.f, 0.f};
#pragma unroll 8
    for (int k = 0; k < H_; ++k) {
      float w = Wph[(size_t)k * C_ + c];
#pragma unroll
      for (int rb = 0; rb < 8; ++rb) acc[rb] += hL[rb * H_ + k] * w;
    }
    float bias = bp[c];
#pragma unroll
    for (int rb = 0; rb < 8; ++rb) out[(size_t)(b0 + rb) * C_ + c] = acc[rb] + bias;
  }
}

extern "C" void kernel_launch(void* const* d_in, const int* in_sizes, int n_in,
                              void* d_out, int out_size, void* d_ws, size_t ws_size,
                              hipStream_t stream) {
  const float* x   = (const float*)d_in[0];
  const float* Wgx = (const float*)d_in[1];
  const float* Wgh = (const float*)d_in[2];
  const float* bg  = (const float*)d_in[3];
  const float* Wix = (const float*)d_in[4];
  const float* Wih = (const float*)d_in[5];
  const float* bi  = (const float*)d_in[6];
  const float* Wfx = (const float*)d_in[7];
  const float* Wfh = (const float*)d_in[8];
  const float* bf_ = (const float*)d_in[9];
  const float* Wox = (const float*)d_in[10];
  const float* Woh = (const float*)d_in[11];
  const float* bo  = (const float*)d_in[12];
  const float* Wph = (const float*)d_in[13];
  const float* bp  = (const float*)d_in[14];
  float* out = (float*)d_out;

  // ws layout: [0, 512KB) h ring (2 slots bf16), then cnt[GB]
  uint16_t* hring = (uint16_t*)d_ws;
  int* cnt = (int*)((char*)d_ws + (size_t)2 * B_ * H_ * sizeof(uint16_t));

  hipMemsetAsync(cnt, 0, GB * sizeof(int), stream);

  lstm_scan<<<dim3(GB * GH), dim3(256), 0, stream>>>(
      x, Wgx, Wgh, bg, Wix, Wih, bi, Wfx, Wfh, bf_, Wox, Woh, bo, hring, cnt);

  const uint16_t* hfin = hring + (size_t)(T_ & 1) * B_ * H_;
  lstm_proj<<<dim3(4, 16), dim3(256), 0, stream>>>(hfin, Wph, bp, out);
}

// Round 3
// 3875.217 us; speedup vs baseline: 6.8060x; 1.2283x over previous
//
#include <hip/hip_runtime.h>
#include <stdint.h>

#define B_ 128
#define T_ 1024
#define D_ 256
#define H_ 512
#define C_ 1000
#define GB 8          // batch groups (16 rows each)
#define GH 32         // hidden-column groups (16 units each)
#define ROWS 16       // batch rows per WG
#define UN 16         // hidden units per WG
#define KTOT (H_ + D_)   // 768: fused [h | x] K dimension
#define NCOL 64          // 4 gates * UN
#define LDK (KTOT + 8)   // padded LDS row stride

typedef __bf16 bf16x8 __attribute__((ext_vector_type(8)));
typedef float f32x4 __attribute__((ext_vector_type(4)));

__device__ __forceinline__ uint16_t f2bf(float f) {
  uint32_t u = __float_as_uint(f);
  u += 0x7FFFu + ((u >> 16) & 1u);   // RNE
  return (uint16_t)(u >> 16);
}
__device__ __forceinline__ float bf2f(uint16_t b) {
  return __uint_as_float(((uint32_t)b) << 16);
}
__device__ __forceinline__ float sigm(float x) { return 1.0f / (1.0f + __expf(-x)); }
__device__ __forceinline__ float tanhfast(float x) { return 2.0f / (1.0f + __expf(-2.0f * x)) - 1.0f; }

// Persistent scan: 256 WGs (1/CU), 256 threads. WG (bb,cg) owns batch rows
// [bb*16,+16) x hidden units [cg*16,+16) for all 4 gates.
// Cross-WG comms through LLC via relaxed system-scope ops only (write-through,
// no wbl2/inv). Sync: per-producer tag words (plain stores after vmcnt(0)) —
// no RMW serialization; consumer wave0 polls its group's 32 tags + __ballot.
// x[t+1] prefetched into registers so HBM latency is off the critical path.
__global__ __launch_bounds__(256, 1) void lstm_scan(
    const float* __restrict__ x,
    const float* __restrict__ Wgx, const float* __restrict__ Wgh, const float* __restrict__ bg,
    const float* __restrict__ Wix, const float* __restrict__ Wih, const float* __restrict__ bi,
    const float* __restrict__ Wfx, const float* __restrict__ Wfh, const float* __restrict__ bf_,
    const float* __restrict__ Wox, const float* __restrict__ Woh, const float* __restrict__ bo,
    uint16_t* __restrict__ hring,   // [2][B_][H_] bf16
    int* __restrict__ tags)         // [GB][GH], zeroed before launch
{
  __shared__ __align__(16) uint16_t WtL[NCOL * LDK];  // Bt[n][k] bf16
  __shared__ __align__(16) uint16_t AL[ROWS * LDK];   // A[m][k] bf16: [h | x]
  __shared__ float gbuf[4 * ROWS * UN];               // gate pre-acts

  const int tid = threadIdx.x;
  const int wg  = blockIdx.x;
  const int bb  = wg & 7;
  const int cg  = wg >> 3;
  const int b0  = bb * ROWS;
  const int u0  = cg * UN;

  const float* Whs[4] = {Wgh, Wih, Wfh, Woh};
  const float* Wxs[4] = {Wgx, Wix, Wfx, Wox};

  // ---- load weight slice into LDS (transposed: Wt[n][k]) ----
  {
    const int n    = tid & 63;
    const int kk   = tid >> 6;        // 0..3
    const int gate = n >> 4;
    const int j    = u0 + (n & 15);
    const float* WhP = Whs[gate];
    const float* WxP = Wxs[gate];
    for (int k4 = 0; k4 < KTOT; k4 += 4) {
      int k = k4 + kk;
      float w = (k < H_) ? WhP[(size_t)k * H_ + j] : WxP[(size_t)(k - H_) * H_ + j];
      WtL[n * LDK + k] = f2bf(w);
    }
  }

  const int sr = tid >> 4;   // staging row 0..15
  const int sj = tid & 15;   // staging chunk 0..15
  const int rr = sr;         // pointwise row
  const int uu = sj;         // pointwise unit

  // thread-pinned state in registers
  float c_reg = 0.0f;
  const float bgr = bg[u0 + uu];
  const float bir = bi[u0 + uu];
  const float bfr = bf_[u0 + uu];
  const float bor = bo[u0 + uu];

  // zero A h-region for t=0 (h[0]==0; never read from global)
  {
    uint64_t* zp = (uint64_t*)&AL[sr * LDK + sj * 32];
#pragma unroll
    for (int j = 0; j < 8; ++j) zp[j] = 0ull;
  }

  const int lane = tid & 63;
  const int wv   = tid >> 6;          // wave = gate
  const int l15  = lane & 15;
  const int q    = lane >> 4;
  const uint16_t* Abase = &AL[l15 * LDK + q * 8];
  const uint16_t* Bbase = &WtL[(wv * UN + l15) * LDK + q * 8];
  int* myTags = &tags[bb * GH + (lane & 31)];

  // ---- prologue: load x[0] into registers ----
  float4 xr0, xr1, xr2, xr3;
  {
    const float* xsrc = x + ((size_t)(b0 + sr) * T_ + 0) * D_ + sj * 16;
    xr0 = ((const float4*)xsrc)[0];
    xr1 = ((const float4*)xsrc)[1];
    xr2 = ((const float4*)xsrc)[2];
    xr3 = ((const float4*)xsrc)[3];
  }

  for (int t = 0; t < T_; ++t) {
    // ---- convert prefetched x[t] -> LDS ----
    {
      uint4 o0, o1;
      o0.x = f2bf(xr0.x) | ((uint32_t)f2bf(xr0.y) << 16);
      o0.y = f2bf(xr0.z) | ((uint32_t)f2bf(xr0.w) << 16);
      o0.z = f2bf(xr1.x) | ((uint32_t)f2bf(xr1.y) << 16);
      o0.w = f2bf(xr1.z) | ((uint32_t)f2bf(xr1.w) << 16);
      o1.x = f2bf(xr2.x) | ((uint32_t)f2bf(xr2.y) << 16);
      o1.y = f2bf(xr2.z) | ((uint32_t)f2bf(xr2.w) << 16);
      o1.z = f2bf(xr3.x) | ((uint32_t)f2bf(xr3.y) << 16);
      o1.w = f2bf(xr3.z) | ((uint32_t)f2bf(xr3.w) << 16);
      uint4* xdst = (uint4*)&AL[sr * LDK + H_ + sj * 16];
      xdst[0] = o0; xdst[1] = o1;
    }
    // ---- issue x[t+1] prefetch (hidden behind the whole step) ----
    {
      const int tn = (t + 1 < T_) ? t + 1 : t;
      const float* xsrc = x + ((size_t)(b0 + sr) * T_ + tn) * D_ + sj * 16;
      xr0 = ((const float4*)xsrc)[0];
      xr1 = ((const float4*)xsrc)[1];
      xr2 = ((const float4*)xsrc)[2];
      xr3 = ((const float4*)xsrc)[3];
    }

    // ---- wait for + stage h[t] ----
    if (t > 0) {
      if (wv == 0) {
        while (true) {
          int v = __hip_atomic_load(myTags, __ATOMIC_RELAXED, __HIP_MEMORY_SCOPE_SYSTEM);
          if (__ballot(v < t) == 0ull) break;
          __builtin_amdgcn_s_sleep(1);
        }
      }
      __syncthreads();
      const uint64_t* hsrc =
          (const uint64_t*)(hring + ((size_t)(t & 1) * B_ + b0 + sr) * H_) + sj * 8;
      uint64_t v[8];
#pragma unroll
      for (int j = 0; j < 8; ++j)
        v[j] = __hip_atomic_load(hsrc + j, __ATOMIC_RELAXED, __HIP_MEMORY_SCOPE_SYSTEM);
      uint64_t* adst = (uint64_t*)&AL[sr * LDK + sj * 32];
#pragma unroll
      for (int j = 0; j < 8; ++j) adst[j] = v[j];
    }
    __syncthreads();

    // ---- GEMM: wave wv -> gate wv pre-acts [16 rows, 16 units] ----
    f32x4 a0 = {0.f, 0.f, 0.f, 0.f};
    f32x4 a1 = {0.f, 0.f, 0.f, 0.f};
    f32x4 a2 = {0.f, 0.f, 0.f, 0.f};
    f32x4 a3 = {0.f, 0.f, 0.f, 0.f};
#pragma unroll
    for (int k0 = 0; k0 < KTOT; k0 += 128) {
      bf16x8 av0 = *(const bf16x8*)(Abase + k0);
      bf16x8 bv0 = *(const bf16x8*)(Bbase + k0);
      bf16x8 av1 = *(const bf16x8*)(Abase + k0 + 32);
      bf16x8 bv1 = *(const bf16x8*)(Bbase + k0 + 32);
      bf16x8 av2 = *(const bf16x8*)(Abase + k0 + 64);
      bf16x8 bv2 = *(const bf16x8*)(Bbase + k0 + 64);
      bf16x8 av3 = *(const bf16x8*)(Abase + k0 + 96);
      bf16x8 bv3 = *(const bf16x8*)(Bbase + k0 + 96);
      a0 = __builtin_amdgcn_mfma_f32_16x16x32_bf16(av0, bv0, a0, 0, 0, 0);
      a1 = __builtin_amdgcn_mfma_f32_16x16x32_bf16(av1, bv1, a1, 0, 0, 0);
      a2 = __builtin_amdgcn_mfma_f32_16x16x32_bf16(av2, bv2, a2, 0, 0, 0);
      a3 = __builtin_amdgcn_mfma_f32_16x16x32_bf16(av3, bv3, a3, 0, 0, 0);
    }
    // D layout: row(batch) = q*4+r, col(unit) = lane&15
#pragma unroll
    for (int r = 0; r < 4; ++r) {
      gbuf[wv * (ROWS * UN) + (q * 4 + r) * UN + l15] =
          (a0[r] + a1[r]) + (a2[r] + a3[r]);
    }
    __syncthreads();

    // ---- pointwise update: thread -> (row rr, unit uu) ----
    {
      const int o  = rr * UN + uu;
      float pg = gbuf[0 * (ROWS * UN) + o] + bgr;
      float pi = gbuf[1 * (ROWS * UN) + o] + bir;
      float pf = gbuf[2 * (ROWS * UN) + o] + bfr;
      float po = gbuf[3 * (ROWS * UN) + o] + bor;
      float g  = tanhfast(pg);
      float ii = sigm(pi);
      float ff = sigm(pf);
      float oo = sigm(po);
      float c  = g * ii + c_reg * ff;
      c_reg = c;
      float h = tanhfast(c) * oo;
      // pack pairs across adjacent lanes; even lanes store 4 B
      uint32_t hb = f2bf(h);
      uint32_t nb = __shfl_down((int)hb, 1);
      if ((tid & 1) == 0) {
        uint32_t pack = hb | (nb << 16);
        uint32_t* gdst = (uint32_t*)(hring +
            ((size_t)((t + 1) & 1) * B_ + b0 + rr) * H_ + u0 + uu);
        __hip_atomic_store(gdst, pack, __ATOMIC_RELAXED, __HIP_MEMORY_SCOPE_SYSTEM);
      }
    }
    asm volatile("s_waitcnt vmcnt(0)" ::: "memory");   // per-wave: h stores done
    __syncthreads();                                   // all waves' stores done
    if (tid == 0) {
      __hip_atomic_store(&tags[bb * GH + cg], t + 1, __ATOMIC_RELAXED,
                         __HIP_MEMORY_SCOPE_SYSTEM);
    }
  }
}

// Final projection: out[b,c] = sum_k h[b,k] * Wph[k,c] + bp[c]
__global__ __launch_bounds__(256) void lstm_proj(
    const uint16_t* __restrict__ hfin,   // [B_][H_] bf16
    const float* __restrict__ Wph,       // [H_][C_]
    const float* __restrict__ bp,        // [C_]
    float* __restrict__ out)             // [B_][C_]
{
  __shared__ float hL[8 * H_];   // 16 KB
  const int tid = threadIdx.x;
  const int b0  = blockIdx.y * 8;
  const int c   = blockIdx.x * 256 + tid;

  {
    int idx = tid * 16;
#pragma unroll
    for (int e = 0; e < 16; ++e) {
      int i = idx + e;
      hL[i] = bf2f(hfin[(size_t)(b0 + (i >> 9)) * H_ + (i & 511)]);
    }
  }
  __syncthreads();

  if (c < C_) {
    float acc[8] = {0.f, 0.f, 0.f, 0.f, 0.f, 0.f, 0.f, 0.f};
#pragma unroll 8
    for (int k = 0; k < H_; ++k) {
      float w = Wph[(size_t)k * C_ + c];
#pragma unroll
      for (int rb = 0; rb < 8; ++rb) acc[rb] += hL[rb * H_ + k] * w;
    }
    float bias = bp[c];
#pragma unroll
    for (int rb = 0; rb < 8; ++rb) out[(size_t)(b0 + rb) * C_ + c] = acc[rb] + bias;
  }
}

extern "C" void kernel_launch(void* const* d_in, const int* in_sizes, int n_in,
                              void* d_out, int out_size, void* d_ws, size_t ws_size,
                              hipStream_t stream) {
  const float* x   = (const float*)d_in[0];
  const float* Wgx = (const float*)d_in[1];
  const float* Wgh = (const float*)d_in[2];
  const float* bg  = (const float*)d_in[3];
  const float* Wix = (const float*)d_in[4];
  const float* Wih = (const float*)d_in[5];
  const float* bi  = (const float*)d_in[6];
  const float* Wfx = (const float*)d_in[7];
  const float* Wfh = (const float*)d_in[8];
  const float* bf_ = (const float*)d_in[9];
  const float* Wox = (const float*)d_in[10];
  const float* Woh = (const float*)d_in[11];
  const float* bo  = (const float*)d_in[12];
  const float* Wph = (const float*)d_in[13];
  const float* bp  = (const float*)d_in[14];
  float* out = (float*)d_out;

  // ws layout: [0, 512KB) h ring (2 slots bf16), then tags[GB*GH]
  uint16_t* hring = (uint16_t*)d_ws;
  int* tags = (int*)((char*)d_ws + (size_t)2 * B_ * H_ * sizeof(uint16_t));

  hipMemsetAsync(tags, 0, GB * GH * sizeof(int), stream);

  lstm_scan<<<dim3(GB * GH), dim3(256), 0, stream>>>(
      x, Wgx, Wgh, bg, Wix, Wih, bi, Wfx, Wfh, bf_, Wox, Woh, bo, hring, tags);

  const uint16_t* hfin = hring + (size_t)(T_ & 1) * B_ * H_;
  lstm_proj<<<dim3(4, 16), dim3(256), 0, stream>>>(hfin, Wph, bp, out);
}

// Round 6
// 3103.448 us; speedup vs baseline: 8.4985x; 1.2487x over previous
//
#include <hip/hip_runtime.h>
#include <stdint.h>

#define B_ 128
#define T_ 1024
#define D_ 256
#define H_ 512
#define C_ 1000
#define GB 8          // batch groups (16 rows each)
#define GH 32         // hidden-column groups (16 units each)
#define ROWS 16       // batch rows per WG
#define UN 16         // hidden units per WG
#define KTOT (H_ + D_)   // 768: fused [h | x] K dimension
#define NCOL 64          // 4 gates * UN
#define LDK (KTOT + 8)   // padded LDS row stride
#define TPAD 32          // tag padding: 32 ints = 128 B = 1 line per tag

typedef __bf16 bf16x8 __attribute__((ext_vector_type(8)));
typedef float f32x4 __attribute__((ext_vector_type(4)));
typedef unsigned int u32x4 __attribute__((ext_vector_type(4)));

__device__ __forceinline__ uint16_t f2bf(float f) {
  uint32_t u = __float_as_uint(f);
  u += 0x7FFFu + ((u >> 16) & 1u);   // RNE
  return (uint16_t)(u >> 16);
}
__device__ __forceinline__ float bf2f(uint16_t b) {
  return __uint_as_float(((uint32_t)b) << 16);
}
__device__ __forceinline__ float sigm(float x) { return 1.0f / (1.0f + __expf(-x)); }
__device__ __forceinline__ float tanhfast(float x) { return 2.0f / (1.0f + __expf(-2.0f * x)) - 1.0f; }

// System-scope (sc0 sc1 = what the compiler emits for system relaxed ops):
// coherence point = LLC. "=&v" early-clobber so outputs never alias addresses.
__device__ __forceinline__ void load_h2x32_sys(const uint16_t* pA, const uint16_t* pB,
                                               u32x4& a, u32x4& b, u32x4& c, u32x4& d) {
  asm volatile("global_load_dwordx4 %0, %4, off sc0 sc1\n\t"
               "global_load_dwordx4 %1, %4, off offset:16 sc0 sc1\n\t"
               "global_load_dwordx4 %2, %5, off sc0 sc1\n\t"
               "global_load_dwordx4 %3, %5, off offset:16 sc0 sc1\n\t"
               "s_waitcnt vmcnt(0)"
               : "=&v"(a), "=&v"(b), "=&v"(c), "=&v"(d)
               : "v"(pA), "v"(pB) : "memory");
}
__device__ __forceinline__ void store_h16_sys(uint16_t* p, u32x4 v) {
  asm volatile("global_store_dwordx4 %0, %1, off sc0 sc1"
               :: "v"(p), "v"(v) : "memory");
}

// Persistent scan: 256 WGs (1/CU), 256 threads. WG (bb,cg) owns batch rows
// [bb*16,+16) x hidden units [cg*16,+16) for all 4 gates.
// All cross-WG comm system-scope through LLC (R3-proven). This round:
//  - tags padded to 1 cache line each (no tag-line contention),
//  - hring re-laid [slot][cg][b][16] so each WG's 512-B publish owns its
//    4 lines exclusively (no false sharing), stored as 32 coalesced
//    dwordx4 from wave 0 only (other waves skip the store-ack drain),
//  - x[t+1] prefetch issued after h staging (off the vmcnt-drain path).
__global__ __launch_bounds__(256, 1) void lstm_scan(
    const float* __restrict__ x,
    const float* __restrict__ Wgx, const float* __restrict__ Wgh, const float* __restrict__ bg,
    const float* __restrict__ Wix, const float* __restrict__ Wih, const float* __restrict__ bi,
    const float* __restrict__ Wfx, const float* __restrict__ Wfh, const float* __restrict__ bf_,
    const float* __restrict__ Wox, const float* __restrict__ Woh, const float* __restrict__ bo,
    uint16_t* __restrict__ hring,   // [2][GH][B_][16] bf16
    int* __restrict__ tags)         // [GB][GH][TPAD], zeroed before launch
{
  __shared__ __align__(16) uint16_t WtL[NCOL * LDK];  // Bt[n][k] bf16
  __shared__ __align__(16) uint16_t AL[ROWS * LDK];   // A[m][k] bf16: [h | x]
  __shared__ float gbuf[4 * ROWS * UN];               // gate pre-acts
  __shared__ __align__(16) uint16_t hOutL[ROWS * UN]; // this WG's h slice

  const int tid = threadIdx.x;
  const int wg  = blockIdx.x;
  const int bb  = wg & 7;
  const int cg  = wg >> 3;
  const int b0  = bb * ROWS;
  const int u0  = cg * UN;

  const float* Whs[4] = {Wgh, Wih, Wfh, Woh};
  const float* Wxs[4] = {Wgx, Wix, Wfx, Wox};

  // ---- load weight slice into LDS (transposed: Wt[n][k]) ----
  {
    const int n    = tid & 63;
    const int kk   = tid >> 6;        // 0..3
    const int gate = n >> 4;
    const int j    = u0 + (n & 15);
    const float* WhP = Whs[gate];
    const float* WxP = Wxs[gate];
    for (int k4 = 0; k4 < KTOT; k4 += 4) {
      int k = k4 + kk;
      float w = (k < H_) ? WhP[(size_t)k * H_ + j] : WxP[(size_t)(k - H_) * H_ + j];
      WtL[n * LDK + k] = f2bf(w);
    }
  }

  const int sr = tid >> 4;   // staging row 0..15
  const int sj = tid & 15;   // staging chunk 0..15
  const int rr = sr;         // pointwise row
  const int uu = sj;         // pointwise unit

  // thread-pinned state in registers
  float c_reg = 0.0f;
  const float bgr = bg[u0 + uu];
  const float bir = bi[u0 + uu];
  const float bfr = bf_[u0 + uu];
  const float bor = bo[u0 + uu];

  // zero A h-region for t=0 (h[0]==0; never read from global)
  {
    uint64_t* zp = (uint64_t*)&AL[sr * LDK + sj * 32];
#pragma unroll
    for (int j = 0; j < 8; ++j) zp[j] = 0ull;
  }

  const int lane = tid & 63;
  const int wv   = tid >> 6;          // wave = gate
  const int l15  = lane & 15;
  const int q    = lane >> 4;
  const uint16_t* Abase = &AL[l15 * LDK + q * 8];
  const uint16_t* Bbase = &WtL[(wv * UN + l15) * LDK + q * 8];
  const int* myTag = &tags[(bb * GH + (lane & 31)) * TPAD];

  // slot stride in shorts for hring[slot][cg][b][16]
  const size_t SLOT = (size_t)GH * B_ * 16;

  // ---- prologue: load x[0] into registers ----
  float4 xr0, xr1, xr2, xr3;
  {
    const float* xsrc = x + ((size_t)(b0 + sr) * T_ + 0) * D_ + sj * 16;
    xr0 = ((const float4*)xsrc)[0];
    xr1 = ((const float4*)xsrc)[1];
    xr2 = ((const float4*)xsrc)[2];
    xr3 = ((const float4*)xsrc)[3];
  }

  __syncthreads();

  for (int t = 0; t < T_; ++t) {
    // ---- convert prefetched x[t] -> LDS ----
    {
      uint4 o0, o1;
      o0.x = f2bf(xr0.x) | ((uint32_t)f2bf(xr0.y) << 16);
      o0.y = f2bf(xr0.z) | ((uint32_t)f2bf(xr0.w) << 16);
      o0.z = f2bf(xr1.x) | ((uint32_t)f2bf(xr1.y) << 16);
      o0.w = f2bf(xr1.z) | ((uint32_t)f2bf(xr1.w) << 16);
      o1.x = f2bf(xr2.x) | ((uint32_t)f2bf(xr2.y) << 16);
      o1.y = f2bf(xr2.z) | ((uint32_t)f2bf(xr2.w) << 16);
      o1.z = f2bf(xr3.x) | ((uint32_t)f2bf(xr3.y) << 16);
      o1.w = f2bf(xr3.z) | ((uint32_t)f2bf(xr3.w) << 16);
      uint4* xdst = (uint4*)&AL[sr * LDK + H_ + sj * 16];
      xdst[0] = o0; xdst[1] = o1;
    }

    // ---- wait for + stage h[t] ----
    if (t > 0) {
      if (wv == 0) {
        while (true) {
          int v = __hip_atomic_load(myTag, __ATOMIC_RELAXED,
                                    __HIP_MEMORY_SCOPE_SYSTEM);
          if (__ballot(v < t) == 0ull) break;
        }
      }
      __syncthreads();
      // thread (sr,sj): units 32sj..32sj+31 of row b0+sr = cg'=2sj, 2sj+1
      const uint16_t* base = hring + (size_t)(t & 1) * SLOT;
      const uint16_t* pA = base + ((2 * sj) * B_ + b0 + sr) * 16;
      const uint16_t* pB = base + ((2 * sj + 1) * B_ + b0 + sr) * 16;
      u32x4 a, b, c, d;
      load_h2x32_sys(pA, pB, a, b, c, d);
      u32x4* adst = (u32x4*)&AL[sr * LDK + sj * 32];
      adst[0] = a; adst[1] = b; adst[2] = c; adst[3] = d;
    }

    // ---- issue x[t+1] prefetch (no vmcnt drain until publish) ----
    {
      const int tn = (t + 1 < T_) ? t + 1 : t;
      const float* xsrc = x + ((size_t)(b0 + sr) * T_ + tn) * D_ + sj * 16;
      xr0 = ((const float4*)xsrc)[0];
      xr1 = ((const float4*)xsrc)[1];
      xr2 = ((const float4*)xsrc)[2];
      xr3 = ((const float4*)xsrc)[3];
    }
    __syncthreads();

    // ---- GEMM: wave wv -> gate wv pre-acts [16 rows, 16 units] ----
    f32x4 a0 = {0.f, 0.f, 0.f, 0.f};
    f32x4 a1 = {0.f, 0.f, 0.f, 0.f};
    f32x4 a2 = {0.f, 0.f, 0.f, 0.f};
    f32x4 a3 = {0.f, 0.f, 0.f, 0.f};
#pragma unroll
    for (int k0 = 0; k0 < KTOT; k0 += 128) {
      bf16x8 av0 = *(const bf16x8*)(Abase + k0);
      bf16x8 bv0 = *(const bf16x8*)(Bbase + k0);
      bf16x8 av1 = *(const bf16x8*)(Abase + k0 + 32);
      bf16x8 bv1 = *(const bf16x8*)(Bbase + k0 + 32);
      bf16x8 av2 = *(const bf16x8*)(Abase + k0 + 64);
      bf16x8 bv2 = *(const bf16x8*)(Bbase + k0 + 64);
      bf16x8 av3 = *(const bf16x8*)(Abase + k0 + 96);
      bf16x8 bv3 = *(const bf16x8*)(Bbase + k0 + 96);
      a0 = __builtin_amdgcn_mfma_f32_16x16x32_bf16(av0, bv0, a0, 0, 0, 0);
      a1 = __builtin_amdgcn_mfma_f32_16x16x32_bf16(av1, bv1, a1, 0, 0, 0);
      a2 = __builtin_amdgcn_mfma_f32_16x16x32_bf16(av2, bv2, a2, 0, 0, 0);
      a3 = __builtin_amdgcn_mfma_f32_16x16x32_bf16(av3, bv3, a3, 0, 0, 0);
    }
    // D layout: row(batch) = q*4+r, col(unit) = lane&15
#pragma unroll
    for (int r = 0; r < 4; ++r) {
      gbuf[wv * (ROWS * UN) + (q * 4 + r) * UN + l15] =
          (a0[r] + a1[r]) + (a2[r] + a3[r]);
    }
    __syncthreads();

    // ---- pointwise update: thread -> (row rr, unit uu) ----
    {
      const int o  = rr * UN + uu;
      float pg = gbuf[0 * (ROWS * UN) + o] + bgr;
      float pi = gbuf[1 * (ROWS * UN) + o] + bir;
      float pf = gbuf[2 * (ROWS * UN) + o] + bfr;
      float po = gbuf[3 * (ROWS * UN) + o] + bor;
      float g  = tanhfast(pg);
      float ii = sigm(pi);
      float ff = sigm(pf);
      float oo = sigm(po);
      float c  = g * ii + c_reg * ff;
      c_reg = c;
      float h = tanhfast(c) * oo;
      hOutL[o] = f2bf(h);
    }
    __syncthreads();

    // ---- publish (wave 0 only): 32 coalesced dwordx4 into this WG's
    //      exclusively-owned 512 B, vmcnt ack, then 1 padded-tag store ----
    if (tid < 32) {
      u32x4 v = *(const u32x4*)&hOutL[tid * 8];
      uint16_t* dst = hring + (size_t)((t + 1) & 1) * SLOT +
                      ((size_t)cg * B_ + b0) * 16 + tid * 8;
      store_h16_sys(dst, v);
      asm volatile("s_waitcnt vmcnt(0)" ::: "memory");
      if (tid == 0) {
        __hip_atomic_store(&tags[(bb * GH + cg) * TPAD], t + 1,
                           __ATOMIC_RELAXED, __HIP_MEMORY_SCOPE_SYSTEM);
      }
    }
    // next step's post-poll barrier orders hOutL reuse (wave0 finishes its
    // stores before it can arrive there)
  }
}

// Final projection: out[b,c] = sum_k h[b,k] * Wph[k,c] + bp[c]
// hfin layout: [GH][B_][16] (slot 0 of hring, since T_ is even)
__global__ __launch_bounds__(256) void lstm_proj(
    const uint16_t* __restrict__ hfin,
    const float* __restrict__ Wph,       // [H_][C_]
    const float* __restrict__ bp,        // [C_]
    float* __restrict__ out)             // [B_][C_]
{
  __shared__ float hL[8 * H_];   // 16 KB
  const int tid = threadIdx.x;
  const int b0  = blockIdx.y * 8;
  const int c   = blockIdx.x * 256 + tid;

  {
    int idx = tid * 16;
#pragma unroll
    for (int e = 0; e < 16; ++e) {
      int i = idx + e;
      int rb = i >> 9, k = i & 511;
      hL[i] = bf2f(hfin[((size_t)(k >> 4) * B_ + b0 + rb) * 16 + (k & 15)]);
    }
  }
  __syncthreads();

  if (c < C_) {
    float acc[8] = {0.f, 0.f, 0.f, 0.f, 0.f, 0.f, 0.f, 0.f};
#pragma unroll 8
    for (int k = 0; k < H_; ++k) {
      float w = Wph[(size_t)k * C_ + c];
#pragma unroll
      for (int rb = 0; rb < 8; ++rb) acc[rb] += hL[rb * H_ + k] * w;
    }
    float bias = bp[c];
#pragma unroll
    for (int rb = 0; rb < 8; ++rb) out[(size_t)(b0 + rb) * C_ + c] = acc[rb] + bias;
  }
}

extern "C" void kernel_launch(void* const* d_in, const int* in_sizes, int n_in,
                              void* d_out, int out_size, void* d_ws, size_t ws_size,
                              hipStream_t stream) {
  const float* x   = (const float*)d_in[0];
  const float* Wgx = (const float*)d_in[1];
  const float* Wgh = (const float*)d_in[2];
  const float* bg  = (const float*)d_in[3];
  const float* Wix = (const float*)d_in[4];
  const float* Wih = (const float*)d_in[5];
  const float* bi  = (const float*)d_in[6];
  const float* Wfx = (const float*)d_in[7];
  const float* Wfh = (const float*)d_in[8];
  const float* bf_ = (const float*)d_in[9];
  const float* Wox = (const float*)d_in[10];
  const float* Woh = (const float*)d_in[11];
  const float* bo  = (const float*)d_in[12];
  const float* Wph = (const float*)d_in[13];
  const float* bp  = (const float*)d_in[14];
  float* out = (float*)d_out;

  // ws: hring [2][GH][B_][16] bf16 (256 KB) | tags [GB][GH][TPAD] (32 KB)
  uint16_t* hring = (uint16_t*)d_ws;
  int* tags = (int*)((char*)d_ws + (size_t)2 * GH * B_ * 16 * sizeof(uint16_t));

  hipMemsetAsync(tags, 0, GB * GH * TPAD * sizeof(int), stream);

  lstm_scan<<<dim3(GB * GH), dim3(256), 0, stream>>>(
      x, Wgx, Wgh, bg, Wix, Wih, bi, Wfx, Wfh, bf_, Wox, Woh, bo, hring, tags);

  // h[T] is in slot T%2 == 0
  const uint16_t* hfin = hring;
  lstm_proj<<<dim3(4, 16), dim3(256), 0, stream>>>(hfin, Wph, bp, out);
}